// Round 11
// baseline (205.672 us; speedup 1.0000x reference)
//
#include <hip/hip_runtime.h>

#define DEV __device__ __forceinline__

constexpr int A_ = 64, DE = 128, M_ = 512, DH = 64;

typedef float vf4 __attribute__((ext_vector_type(4)));  // native vector for nt builtins

DEV float wred_sum64(float v) {
#pragma unroll
    for (int o = 1; o < 64; o <<= 1) v += __shfl_xor(v, o, 64);
    return v;
}

DEV float4 nt_load4(const float* p) {
    vf4 r = __builtin_nontemporal_load((const vf4*)p);
    return make_float4(r.x, r.y, r.z, r.w);
}

// ---------------- Kernel 1: per-(b,m) hyperbolic dH2 + log_map ----------------
// one wave per (b,m) row; lane = dim (dh=64)
__global__ __launch_bounds__(256) void k_hyp(const float* __restrict__ curr_hyp,
                                             const float* __restrict__ demo_hyp,
                                             float* __restrict__ dH2,
                                             float* __restrict__ logv) {
    const int lane = threadIdx.x & 63;
    const int r    = (blockIdx.x << 2) + (threadIdx.x >> 6);  // [0, B*M)
    const int b    = r >> 9;                                  // M=512

    float x = curr_hyp[(b << 6) + lane];
    float y = demo_hyp[((size_t)r << 6) + lane];
    const float mx = 1.0f - 1e-5f;

    float x2r = wred_sum64(x * x);
    float xn  = fmaxf(sqrtf(x2r), 1e-15f);
    float sx  = xn > mx ? mx / xn : 1.0f;
    x *= sx;
    float x2 = x2r * sx * sx;
    float y2r = wred_sum64(y * y);
    float yn  = fmaxf(sqrtf(y2r), 1e-15f);
    float sy  = yn > mx ? mx / yn : 1.0f;
    y *= sy;
    float y2 = y2r * sy * sy;

    float xy = wred_sum64(x * y);
    float num = (1.f - 2.f * xy + y2) * (-x) + (1.f - x2) * y;
    float den = fmaxf(1.f - 2.f * xy + x2 * y2, 1e-15f);
    float u   = num / den;

    float u2  = wred_sum64(u * u);
    float un  = fmaxf(sqrtf(u2), 1e-15f);
    float arg = fminf(un, 1.f - 1e-7f);
    float at  = 0.5f * __logf((1.f + arg) / (1.f - arg));  // atanh

    if (lane == 0) dH2[r] = 4.f * at * at;

    float lamden = fmaxf(1.f - x2, 1e-15f);  // 2/lambda
    float ls     = lamden * at / un;
    logv[((size_t)r << 6) + lane] = ls * u;
}

// ---------------- Kernel 2: round-10 monolith (nt loads) + depth-4 prefetch ----------------
// one block per (b,a); 512 threads = 8 waves. Identical to the 203.0us round-10 kernel
// except the register prefetch pipeline is depth-4: 4 KB in flight per wave (vs 2 KB),
// testing whether outstanding-request count binds now that nt removed L2 allocation.
__global__ __launch_bounds__(512, 4) void k_main(const float* __restrict__ curr_rho,
                                                 const float* __restrict__ demo_rho,
                                                 const float* __restrict__ curr_hyp,
                                                 const float* __restrict__ dH2,
                                                 const float* __restrict__ logv,
                                                 const float* __restrict__ We,
                                                 const float* __restrict__ Wh,
                                                 const float* __restrict__ gamma,
                                                 const float* __restrict__ beta,
                                                 float* __restrict__ out) {
    __shared__ __align__(16) float rede[32 * 132];  // e_acc reduce scratch, padded stride
    __shared__ float lds_sc[512];
    __shared__ float lds_dh[512];
    __shared__ float redm[8];
    __shared__ float reds[8];
    __shared__ float vpart[8][64];
    __shared__ float eh[192];  // [0:128) e_out, [128:192) h

    const int t    = threadIdx.x;
    const int lane = t & 63;
    const int wv   = t >> 6;
    const int dp   = t & 15;
    const int mi   = t >> 4;           // 0..31
    const int blk  = blockIdx.x;
    const int b    = blk >> 6, a = blk & 63;

    lds_dh[t] = dH2[(b << 9) + t];

    float qf[8];
    {
        float4 q0 = *(const float4*)(curr_rho + (size_t)blk * DE + dp * 8);
        float4 q1 = *(const float4*)(curr_rho + (size_t)blk * DE + dp * 8 + 4);
        qf[0] = q0.x; qf[1] = q0.y; qf[2] = q0.z; qf[3] = q0.w;
        qf[4] = q1.x; qf[5] = q1.y; qf[6] = q1.z; qf[7] = q1.w;
    }

    // per-thread streaming pointer: this thread's 32B slice of row mi of each chunk
    const size_t rowStride = (size_t)A_ * DE;        // 8192 floats
    const size_t cstep     = (size_t)32 * rowStride; // floats per 32-m chunk
    const float* tp = demo_rho + ((size_t)b * M_ * A_ + a) * DE + (size_t)mi * rowStride + dp * 8;

    __syncthreads();  // lds_dh visible to all waves (only pre-loop barrier)

    // depth-4 register prefetch pipeline, nontemporal loads
    float4 p0a = nt_load4(tp);
    float4 p0b = nt_load4(tp + 4);
    float4 p1a = nt_load4(tp + cstep);
    float4 p1b = nt_load4(tp + cstep + 4);
    float4 p2a = nt_load4(tp + 2 * cstep);
    float4 p2b = nt_load4(tp + 2 * cstep + 4);
    float4 p3a = nt_load4(tp + 3 * cstep);
    float4 p3b = nt_load4(tp + 3 * cstep + 4);

    float e_acc[8];
#pragma unroll
    for (int j = 0; j < 8; j++) e_acc[j] = 0.f;
    float gmax = -1e30f, gsum = 0.f;  // per-WAVE running max/sum

#pragma unroll 4
    for (int c = 0; c < 16; ++c) {
        float4 n0, n1;
        if (c + 4 < 16) {  // issue chunk c+4 loads; 4 chunks stay in flight
            const float* np = tp + (size_t)(c + 4) * cstep;
            n0 = nt_load4(np);
            n1 = nt_load4(np + 4);
        }
        float kf[8];
        kf[0] = p0a.x; kf[1] = p0a.y; kf[2] = p0a.z; kf[3] = p0a.w;
        kf[4] = p0b.x; kf[5] = p0b.y; kf[6] = p0b.z; kf[7] = p0b.w;

        float ps = 0.f;
#pragma unroll
        for (int j = 0; j < 8; j++) { float d = qf[j] - kf[j]; ps += d * d; }
        ps += __shfl_xor(ps, 1, 64);
        ps += __shfl_xor(ps, 2, 64);
        ps += __shfl_xor(ps, 4, 64);
        ps += __shfl_xor(ps, 8, 64);  // uniform over dp
        float sc = -(lds_dh[c * 32 + mi] + ps);
        if (dp == 0) lds_sc[c * 32 + mi] = sc;  // raw score for the v-step later

        // wave-local online softmax over this wave's 4 rows (lane bits 4,5)
        float lm = fmaxf(sc, __shfl_xor(sc, 16, 64));
        lm = fmaxf(lm, __shfl_xor(lm, 32, 64));
        float gnew = fmaxf(gmax, lm);
        float r1   = __expf(gmax - gnew);    // first chunk: exp(-inf)=0
        float wexp = __expf(sc - gnew);
        float wsum = wexp + __shfl_xor(wexp, 16, 64);
        wsum += __shfl_xor(wsum, 32, 64);
        gsum = fmaf(gsum, r1, wsum);
#pragma unroll
        for (int j = 0; j < 8; j++) e_acc[j] = fmaf(wexp, kf[j], e_acc[j] * r1);
        gmax = gnew;

        // rotate pipeline
        p0a = p1a; p0b = p1b;
        p1a = p2a; p1b = p2b;
        p2a = p3a; p2b = p3b;
        p3a = n0;  p3b = n1;
    }

    // ---- flash combine across the 8 waves ----
    if (lane == 0) { redm[wv] = gmax; reds[wv] = gsum; }
    __syncthreads();  // also covers lds_sc writes

    float M = redm[0];
#pragma unroll
    for (int w = 1; w < 8; w++) M = fmaxf(M, redm[w]);
    float S = 0.f;
#pragma unroll
    for (int w = 0; w < 8; w++) S += reds[w] * __expf(redm[w] - M);
    const float inv = 1.f / S;                 // block-uniform
    const float fw  = __expf(gmax - M);        // wave-uniform rescale of its partials

    float al = __expf(lds_sc[t] - M) * inv;    // alpha for own slot

    // reduce e_acc across the 32 mi-groups (pre-scaled by wave factor fw)
    *(float4*)&rede[mi * 132 + dp * 8] =
        make_float4(e_acc[0] * fw, e_acc[1] * fw, e_acc[2] * fw, e_acc[3] * fw);
    *(float4*)&rede[mi * 132 + dp * 8 + 4] =
        make_float4(e_acc[4] * fw, e_acc[5] * fw, e_acc[6] * fw, e_acc[7] * fw);
    lds_sc[t] = al;  // same-wave readers below
    __syncthreads();

    if (t < 128) {
        float s = 0.f;
#pragma unroll
        for (int g = 0; g < 32; g++) s += rede[g * 132 + t];
        eh[t] = s * inv;
    }

    // v = alpha @ logv : wave wv handles m in [wv*64, wv*64+64), lane = dh dim
    {
        const float* lvb = logv + ((size_t)(b * M_) + wv * 64) * DH;
        float acc = 0.f;
#pragma unroll 8
        for (int i = 0; i < 64; ++i)
            acc = fmaf(lds_sc[wv * 64 + i], lvb[(size_t)i * DH + lane], acc);
        vpart[wv][lane] = acc;
    }
    __syncthreads();

    if (wv == 0) {
        float v = 0.f;
#pragma unroll
        for (int w = 0; w < 8; w++) v += vpart[w][lane];

        const float mx = 1.0f - 1e-5f;
        float x = curr_hyp[(b << 6) + lane];
        float x2r = wred_sum64(x * x);
        float xn  = fmaxf(sqrtf(x2r), 1e-15f);
        float sx  = xn > mx ? mx / xn : 1.f;
        x *= sx;
        float x2 = x2r * sx * sx;
        float lamden = fmaxf(1.f - x2, 1e-15f);  // 2/lambda

        float v2 = wred_sum64(v * v);
        float vn = fmaxf(sqrtf(v2), 1e-15f);
        float targ   = vn / lamden;              // lambda*vnorm/2
        float e2     = __expf(2.f * targ);
        float factor = 1.f - 2.f / (e2 + 1.f);   // tanh, inf-safe
        float wvv    = v * (factor / vn);

        float w2 = wred_sum64(wvv * wvv);
        float xw = wred_sum64(x * wvv);
        float num = (1.f + 2.f * xw + w2) * x + (1.f - x2) * wvv;
        float den = fmaxf(1.f + 2.f * xw + x2 * w2, 1e-15f);
        float h   = num / den;
        float h2  = wred_sum64(h * h);
        float hn  = fmaxf(sqrtf(h2), 1e-15f);
        float shh = hn > mx ? mx / hn : 1.f;
        h *= shh;
        eh[128 + lane] = h;  // same-wave visibility

        float ze = 0.f;
        const float* werow = We + lane * 128;
#pragma unroll
        for (int d0 = 0; d0 < 128; d0 += 4) {
            float4 wv4 = *(const float4*)(werow + d0);
            ze = fmaf(eh[d0 + 0], wv4.x, ze);
            ze = fmaf(eh[d0 + 1], wv4.y, ze);
            ze = fmaf(eh[d0 + 2], wv4.z, ze);
            ze = fmaf(eh[d0 + 3], wv4.w, ze);
        }
        float zh = 0.f;
        const float* whrow = Wh + lane * 64;
#pragma unroll
        for (int d0 = 0; d0 < 64; d0 += 4) {
            float4 wv4 = *(const float4*)(whrow + d0);
            zh = fmaf(eh[128 + d0 + 0], wv4.x, zh);
            zh = fmaf(eh[128 + d0 + 1], wv4.y, zh);
            zh = fmaf(eh[128 + d0 + 2], wv4.z, zh);
            zh = fmaf(eh[128 + d0 + 3], wv4.w, zh);
        }
        float ssum = wred_sum64(ze + zh);
        float mean = ssum * (1.f / 128.f);
        float sq   = wred_sum64(ze * ze + zh * zh);
        float var  = sq * (1.f / 128.f) - mean * mean;
        float rinv = rsqrtf(var + 1e-5f);
        float oe = (ze - mean) * rinv * gamma[lane] + beta[lane];
        float oh = (zh - mean) * rinv * gamma[64 + lane] + beta[64 + lane];
        out[(size_t)blk * 128 + lane]      = oe;
        out[(size_t)blk * 128 + 64 + lane] = oh;
    }
}

extern "C" void kernel_launch(void* const* d_in, const int* in_sizes, int n_in,
                              void* d_out, int out_size, void* d_ws, size_t ws_size,
                              hipStream_t stream) {
    const float* curr_rho = (const float*)d_in[0];
    const float* curr_hyp = (const float*)d_in[1];
    const float* demo_rho = (const float*)d_in[2];
    const float* demo_hyp = (const float*)d_in[3];
    const float* We       = (const float*)d_in[4];
    const float* Wh       = (const float*)d_in[5];
    const float* gamma    = (const float*)d_in[6];
    const float* beta     = (const float*)d_in[7];
    float* out = (float*)d_out;

    float* ws   = (float*)d_ws;
    float* dH2  = ws;            // 4096 floats
    float* logv = ws + 4096;     // 262144 floats

    k_hyp<<<1024, 256, 0, stream>>>(curr_hyp, demo_hyp, dH2, logv);
    k_main<<<512, 512, 0, stream>>>(curr_rho, demo_rho, curr_hyp, dH2, logv,
                                    We, Wh, gamma, beta, out);
}

// Round 12
// 204.393 us; speedup vs baseline: 1.0063x; 1.0063x over previous
//
#include <hip/hip_runtime.h>

#define DEV __device__ __forceinline__

constexpr int A_ = 64, DE = 128, M_ = 512, DH = 64;

typedef float vf4 __attribute__((ext_vector_type(4)));  // native vector for nt builtins

DEV float wred_sum64(float v) {
#pragma unroll
    for (int o = 1; o < 64; o <<= 1) v += __shfl_xor(v, o, 64);
    return v;
}

DEV float4 nt_load4(const float* p) {
    vf4 r = __builtin_nontemporal_load((const vf4*)p);
    return make_float4(r.x, r.y, r.z, r.w);
}

// ---------------- Kernel 1: per-(b,m) hyperbolic dH2 + log_map ----------------
// one wave per (b,m) row; lane = dim (dh=64)
__global__ __launch_bounds__(256) void k_hyp(const float* __restrict__ curr_hyp,
                                             const float* __restrict__ demo_hyp,
                                             float* __restrict__ dH2,
                                             float* __restrict__ logv) {
    const int lane = threadIdx.x & 63;
    const int r    = (blockIdx.x << 2) + (threadIdx.x >> 6);  // [0, B*M)
    const int b    = r >> 9;                                  // M=512

    float x = curr_hyp[(b << 6) + lane];
    float y = demo_hyp[((size_t)r << 6) + lane];
    const float mx = 1.0f - 1e-5f;

    float x2r = wred_sum64(x * x);
    float xn  = fmaxf(sqrtf(x2r), 1e-15f);
    float sx  = xn > mx ? mx / xn : 1.0f;
    x *= sx;
    float x2 = x2r * sx * sx;
    float y2r = wred_sum64(y * y);
    float yn  = fmaxf(sqrtf(y2r), 1e-15f);
    float sy  = yn > mx ? mx / yn : 1.0f;
    y *= sy;
    float y2 = y2r * sy * sy;

    float xy = wred_sum64(x * y);
    float num = (1.f - 2.f * xy + y2) * (-x) + (1.f - x2) * y;
    float den = fmaxf(1.f - 2.f * xy + x2 * y2, 1e-15f);
    float u   = num / den;

    float u2  = wred_sum64(u * u);
    float un  = fmaxf(sqrtf(u2), 1e-15f);
    float arg = fminf(un, 1.f - 1e-7f);
    float at  = 0.5f * __logf((1.f + arg) / (1.f - arg));  // atanh

    if (lane == 0) dH2[r] = 4.f * at * at;

    float lamden = fmaxf(1.f - x2, 1e-15f);  // 2/lambda
    float ls     = lamden * at / un;
    logv[((size_t)r << 6) + lane] = ls * u;
}

// ---------------- Kernel 2: round-1 monolith + NONTEMPORAL streaming loads ----------------
// one block per (b,a); 512 threads = 8 waves. The harness-verified best (203.0 us):
// round-1 structure (depth-2 register prefetch — depth-4 tested worse in BOTH cache
// regimes, r8/r11) with nontemporal (L2 no-allocate) loads on the six demo_rho load
// sites (134 MB zero-reuse stream; nt = -7 us, r10).
__global__ __launch_bounds__(512, 4) void k_main(const float* __restrict__ curr_rho,
                                                 const float* __restrict__ demo_rho,
                                                 const float* __restrict__ curr_hyp,
                                                 const float* __restrict__ dH2,
                                                 const float* __restrict__ logv,
                                                 const float* __restrict__ We,
                                                 const float* __restrict__ Wh,
                                                 const float* __restrict__ gamma,
                                                 const float* __restrict__ beta,
                                                 float* __restrict__ out) {
    __shared__ __align__(16) float rede[32 * 132];  // e_acc reduce scratch, padded stride
    __shared__ float lds_sc[512];
    __shared__ float lds_dh[512];
    __shared__ float redm[8];
    __shared__ float reds[8];
    __shared__ float vpart[8][64];
    __shared__ float eh[192];  // [0:128) e_out, [128:192) h

    const int t    = threadIdx.x;
    const int lane = t & 63;
    const int wv   = t >> 6;
    const int dp   = t & 15;
    const int mi   = t >> 4;           // 0..31
    const int blk  = blockIdx.x;
    const int b    = blk >> 6, a = blk & 63;

    lds_dh[t] = dH2[(b << 9) + t];

    float qf[8];
    {
        float4 q0 = *(const float4*)(curr_rho + (size_t)blk * DE + dp * 8);
        float4 q1 = *(const float4*)(curr_rho + (size_t)blk * DE + dp * 8 + 4);
        qf[0] = q0.x; qf[1] = q0.y; qf[2] = q0.z; qf[3] = q0.w;
        qf[4] = q1.x; qf[5] = q1.y; qf[6] = q1.z; qf[7] = q1.w;
    }

    // per-thread streaming pointer: this thread's 32B slice of row mi of each chunk
    const size_t rowStride = (size_t)A_ * DE;        // 8192 floats
    const size_t cstep     = (size_t)32 * rowStride; // floats per 32-m chunk
    const float* tp = demo_rho + ((size_t)b * M_ * A_ + a) * DE + (size_t)mi * rowStride + dp * 8;

    __syncthreads();  // lds_dh visible to all waves (only pre-loop barrier)

    // depth-2 register prefetch pipeline (r1-proven), nontemporal loads
    float4 ka0 = nt_load4(tp);
    float4 ka1 = nt_load4(tp + 4);
    float4 kb0 = nt_load4(tp + cstep);
    float4 kb1 = nt_load4(tp + cstep + 4);

    float e_acc[8];
#pragma unroll
    for (int j = 0; j < 8; j++) e_acc[j] = 0.f;
    float gmax = -1e30f, gsum = 0.f;  // per-WAVE running max/sum

#pragma unroll 2
    for (int c = 0; c < 16; ++c) {
        float4 n0, n1;
        if (c + 2 < 16) {  // issue chunk c+2 loads; in flight across this chunk's compute
            const float* np = tp + (size_t)(c + 2) * cstep;
            n0 = nt_load4(np);
            n1 = nt_load4(np + 4);
        }
        float kf[8];
        kf[0] = ka0.x; kf[1] = ka0.y; kf[2] = ka0.z; kf[3] = ka0.w;
        kf[4] = ka1.x; kf[5] = ka1.y; kf[6] = ka1.z; kf[7] = ka1.w;

        float ps = 0.f;
#pragma unroll
        for (int j = 0; j < 8; j++) { float d = qf[j] - kf[j]; ps += d * d; }
        ps += __shfl_xor(ps, 1, 64);
        ps += __shfl_xor(ps, 2, 64);
        ps += __shfl_xor(ps, 4, 64);
        ps += __shfl_xor(ps, 8, 64);  // uniform over dp
        float sc = -(lds_dh[c * 32 + mi] + ps);
        if (dp == 0) lds_sc[c * 32 + mi] = sc;  // raw score for the v-step later

        // wave-local online softmax over this wave's 4 rows (lane bits 4,5)
        float lm = fmaxf(sc, __shfl_xor(sc, 16, 64));
        lm = fmaxf(lm, __shfl_xor(lm, 32, 64));
        float gnew = fmaxf(gmax, lm);
        float r1   = __expf(gmax - gnew);    // first chunk: exp(-inf)=0
        float wexp = __expf(sc - gnew);
        float wsum = wexp + __shfl_xor(wexp, 16, 64);
        wsum += __shfl_xor(wsum, 32, 64);
        gsum = fmaf(gsum, r1, wsum);
#pragma unroll
        for (int j = 0; j < 8; j++) e_acc[j] = fmaf(wexp, kf[j], e_acc[j] * r1);
        gmax = gnew;

        // rotate pipeline
        ka0 = kb0; ka1 = kb1; kb0 = n0; kb1 = n1;
    }

    // ---- flash combine across the 8 waves ----
    if (lane == 0) { redm[wv] = gmax; reds[wv] = gsum; }
    __syncthreads();  // also covers lds_sc writes

    float M = redm[0];
#pragma unroll
    for (int w = 1; w < 8; w++) M = fmaxf(M, redm[w]);
    float S = 0.f;
#pragma unroll
    for (int w = 0; w < 8; w++) S += reds[w] * __expf(redm[w] - M);
    const float inv = 1.f / S;                 // block-uniform
    const float fw  = __expf(gmax - M);        // wave-uniform rescale of its partials

    float al = __expf(lds_sc[t] - M) * inv;    // alpha for own slot

    // reduce e_acc across the 32 mi-groups (pre-scaled by wave factor fw)
    *(float4*)&rede[mi * 132 + dp * 8] =
        make_float4(e_acc[0] * fw, e_acc[1] * fw, e_acc[2] * fw, e_acc[3] * fw);
    *(float4*)&rede[mi * 132 + dp * 8 + 4] =
        make_float4(e_acc[4] * fw, e_acc[5] * fw, e_acc[6] * fw, e_acc[7] * fw);
    lds_sc[t] = al;  // same-wave readers below
    __syncthreads();

    if (t < 128) {
        float s = 0.f;
#pragma unroll
        for (int g = 0; g < 32; g++) s += rede[g * 132 + t];
        eh[t] = s * inv;
    }

    // v = alpha @ logv : wave wv handles m in [wv*64, wv*64+64), lane = dh dim
    {
        const float* lvb = logv + ((size_t)(b * M_) + wv * 64) * DH;
        float acc = 0.f;
#pragma unroll 8
        for (int i = 0; i < 64; ++i)
            acc = fmaf(lds_sc[wv * 64 + i], lvb[(size_t)i * DH + lane], acc);
        vpart[wv][lane] = acc;
    }
    __syncthreads();

    if (wv == 0) {
        float v = 0.f;
#pragma unroll
        for (int w = 0; w < 8; w++) v += vpart[w][lane];

        const float mx = 1.0f - 1e-5f;
        float x = curr_hyp[(b << 6) + lane];
        float x2r = wred_sum64(x * x);
        float xn  = fmaxf(sqrtf(x2r), 1e-15f);
        float sx  = xn > mx ? mx / xn : 1.f;
        x *= sx;
        float x2 = x2r * sx * sx;
        float lamden = fmaxf(1.f - x2, 1e-15f);  // 2/lambda

        float v2 = wred_sum64(v * v);
        float vn = fmaxf(sqrtf(v2), 1e-15f);
        float targ   = vn / lamden;              // lambda*vnorm/2
        float e2     = __expf(2.f * targ);
        float factor = 1.f - 2.f / (e2 + 1.f);   // tanh, inf-safe
        float wvv    = v * (factor / vn);

        float w2 = wred_sum64(wvv * wvv);
        float xw = wred_sum64(x * wvv);
        float num = (1.f + 2.f * xw + w2) * x + (1.f - x2) * wvv;
        float den = fmaxf(1.f + 2.f * xw + x2 * w2, 1e-15f);
        float h   = num / den;
        float h2  = wred_sum64(h * h);
        float hn  = fmaxf(sqrtf(h2), 1e-15f);
        float shh = hn > mx ? mx / hn : 1.f;
        h *= shh;
        eh[128 + lane] = h;  // same-wave visibility

        float ze = 0.f;
        const float* werow = We + lane * 128;
#pragma unroll
        for (int d0 = 0; d0 < 128; d0 += 4) {
            float4 wv4 = *(const float4*)(werow + d0);
            ze = fmaf(eh[d0 + 0], wv4.x, ze);
            ze = fmaf(eh[d0 + 1], wv4.y, ze);
            ze = fmaf(eh[d0 + 2], wv4.z, ze);
            ze = fmaf(eh[d0 + 3], wv4.w, ze);
        }
        float zh = 0.f;
        const float* whrow = Wh + lane * 64;
#pragma unroll
        for (int d0 = 0; d0 < 64; d0 += 4) {
            float4 wv4 = *(const float4*)(whrow + d0);
            zh = fmaf(eh[128 + d0 + 0], wv4.x, zh);
            zh = fmaf(eh[128 + d0 + 1], wv4.y, zh);
            zh = fmaf(eh[128 + d0 + 2], wv4.z, zh);
            zh = fmaf(eh[128 + d0 + 3], wv4.w, zh);
        }
        float ssum = wred_sum64(ze + zh);
        float mean = ssum * (1.f / 128.f);
        float sq   = wred_sum64(ze * ze + zh * zh);
        float var  = sq * (1.f / 128.f) - mean * mean;
        float rinv = rsqrtf(var + 1e-5f);
        float oe = (ze - mean) * rinv * gamma[lane] + beta[lane];
        float oh = (zh - mean) * rinv * gamma[64 + lane] + beta[64 + lane];
        out[(size_t)blk * 128 + lane]      = oe;
        out[(size_t)blk * 128 + 64 + lane] = oh;
    }
}

extern "C" void kernel_launch(void* const* d_in, const int* in_sizes, int n_in,
                              void* d_out, int out_size, void* d_ws, size_t ws_size,
                              hipStream_t stream) {
    const float* curr_rho = (const float*)d_in[0];
    const float* curr_hyp = (const float*)d_in[1];
    const float* demo_rho = (const float*)d_in[2];
    const float* demo_hyp = (const float*)d_in[3];
    const float* We       = (const float*)d_in[4];
    const float* Wh       = (const float*)d_in[5];
    const float* gamma    = (const float*)d_in[6];
    const float* beta     = (const float*)d_in[7];
    float* out = (float*)d_out;

    float* ws   = (float*)d_ws;
    float* dH2  = ws;            // 4096 floats
    float* logv = ws + 4096;     // 262144 floats

    k_hyp<<<1024, 256, 0, stream>>>(curr_hyp, demo_hyp, dH2, logv);
    k_main<<<512, 512, 0, stream>>>(curr_rho, demo_rho, curr_hyp, dH2, logv,
                                    We, Wh, gamma, beta, out);
}